// Round 6
// baseline (635.999 us; speedup 1.0000x reference)
//
#include <hip/hip_runtime.h>
#include <float.h>

// Problem constants: B=32 L=1024 D=128 K=1024
#define NTOK 32768
#define DDIM 128
#define KCODES 1024
#define PZ 68           // zt pitch: mult of 4 -> 16B-aligned ds_read_b128; stores lane=token -> 2-way (free)

// Optimization barrier: blocks fma-contraction/reassociation so we replicate
// numpy's exact fp32 rounding sequence (argmin must match numpy bit-for-bit).
__device__ __forceinline__ float nofuse(float x) { asm volatile("" : "+v"(x)); return x; }

// ---------------- prep: cbT[d][k] transpose + cnorm (numpy pairwise) --------
__global__ void prep_cb(const float* __restrict__ cb, float* __restrict__ cbT,
                        float* __restrict__ cnorm, float* __restrict__ loss_accum) {
    __shared__ float rows[32 * 129];
    const int tid = threadIdx.x;
    const int k0 = blockIdx.x * 32;
    if (blockIdx.x == 0 && tid == 0) loss_accum[0] = 0.0f;   // replaces memset dispatch
    #pragma unroll
    for (int it = 0; it < 4; ++it) {
        int g = it * 256 + tid;          // 0..1023 float4
        int r = g >> 5, d4 = g & 31;
        float4 v = *(const float4*)(cb + (size_t)(k0 + r) * DDIM + 4 * d4);
        rows[r * 129 + 4 * d4 + 0] = v.x;
        rows[r * 129 + 4 * d4 + 1] = v.y;
        rows[r * 129 + 4 * d4 + 2] = v.z;
        rows[r * 129 + 4 * d4 + 3] = v.w;
    }
    __syncthreads();
    #pragma unroll
    for (int it = 0; it < 4; ++it) {
        int h = it * 256 + tid;          // 0..1023
        int d = h >> 3, c4 = h & 7;
        float4 v;
        v.x = rows[(4 * c4 + 0) * 129 + d];
        v.y = rows[(4 * c4 + 1) * 129 + d];
        v.z = rows[(4 * c4 + 2) * 129 + d];
        v.w = rows[(4 * c4 + 3) * 129 + d];
        *(float4*)(cbT + (size_t)d * KCODES + k0 + 4 * c4) = v;
    }
    if (tid < 32) {
        const float* p = &rows[tid * 129];
        float r[8];
        #pragma unroll
        for (int j = 0; j < 8; ++j) { float v = p[j]; r[j] = nofuse(v * v); }
        #pragma unroll
        for (int i = 8; i < DDIM; i += 8) {
            #pragma unroll
            for (int j = 0; j < 8; ++j) {
                float v = p[i + j];
                r[j] = nofuse(r[j] + nofuse(v * v));
            }
        }
        float s01 = nofuse(r[0] + r[1]);
        float s23 = nofuse(r[2] + r[3]);
        float s45 = nofuse(r[4] + r[5]);
        float s67 = nofuse(r[6] + r[7]);
        cnorm[k0 + tid] = nofuse(nofuse(s01 + s23) + nofuse(s45 + s67));
    }
}

// ---------------- fully fused: dist+argmin+gather+loss+z_q ------------------
// 512 blocks x 256 thr; block = 64 tokens x all 1024 codes (4 passes of 256).
// dist(t,k) = fl( fl(zn_t + cn_k) - 2*dot ), dot = single fmaf chain d=0..127
// ascending — bit-identical distances/indices to R2/R3/R5 (all passed).
__global__ __launch_bounds__(256, 4)
void vq_fused(const float* __restrict__ z, const float* __restrict__ cb,
              const float* __restrict__ cbT, const float* __restrict__ cnorm,
              float* __restrict__ zq, float* __restrict__ idxf,
              float* __restrict__ loss_accum) {
    __shared__ float zt[DDIM * PZ];      // [d][token], 34816 B -> 4 blocks/CU
    __shared__ float zn_s[64];
    __shared__ float sm[4];

    const int tid  = threadIdx.x;
    const int tx   = tid & 31;           // code group: codes 8*tx..8*tx+7 (+pass*256)
    const int ty   = tid >> 5;           // token group: tokens 8*ty..8*ty+7
    const int lane = tid & 63;
    const int wv   = tid >> 6;
    const int t0   = blockIdx.x * 64;

    // ---- stage zt transposed; lane=token stores -> 2-way bank (free) ----
    #pragma unroll
    for (int q = 0; q < 8; ++q) {
        int d4 = wv * 8 + q;
        float4 v = *(const float4*)(z + (size_t)(t0 + lane) * DDIM + 4 * d4);
        zt[(4 * d4 + 0) * PZ + lane] = v.x;
        zt[(4 * d4 + 1) * PZ + lane] = v.y;
        zt[(4 * d4 + 2) * PZ + lane] = v.z;
        zt[(4 * d4 + 3) * PZ + lane] = v.w;
    }
    __syncthreads();

    // ---- zn per token, exact numpy pairwise order ----
    if (tid < 64) {
        float rr[8];
        #pragma unroll
        for (int j = 0; j < 8; ++j) { float v = zt[j * PZ + tid]; rr[j] = nofuse(v * v); }
        #pragma unroll
        for (int i = 1; i < 16; ++i)
            #pragma unroll
            for (int j = 0; j < 8; ++j) {
                float v = zt[(8 * i + j) * PZ + tid];
                rr[j] = nofuse(rr[j] + nofuse(v * v));
            }
        float s01 = nofuse(rr[0] + rr[1]);
        float s23 = nofuse(rr[2] + rr[3]);
        float s45 = nofuse(rr[4] + rr[5]);
        float s67 = nofuse(rr[6] + rr[7]);
        zn_s[tid] = nofuse(nofuse(s01 + s23) + nofuse(s45 + s67));
    }
    __syncthreads();

    float minv[8];
    int   mini[8];
    #pragma unroll
    for (int i = 0; i < 8; ++i) { minv[i] = FLT_MAX; mini[i] = 0; }

    // ---- 4 passes of 256 codes; depth-4 software-pipelined cbT stream ----
    for (int p = 0; p < 4; ++p) {
        const int kbp = p * 256;
        const float* cp = cbT + kbp + 8 * tx;

        float acc[8][8];
        #pragma unroll
        for (int i = 0; i < 8; ++i)
            #pragma unroll
            for (int j = 0; j < 8; ++j) acc[i][j] = 0.0f;

        float4 pf0[4], pf1[4];           // register ring: 4 d-iters in flight
        #pragma unroll
        for (int d = 0; d < 4; ++d) {
            pf0[d] = *(const float4*)(cp + (size_t)d * KCODES);
            pf1[d] = *(const float4*)(cp + (size_t)d * KCODES + 4);
        }

        #pragma unroll 4
        for (int d = 0; d < DDIM - 4; ++d) {
            const int slot = d & 3;
            float4 c0 = pf0[slot], c1 = pf1[slot];
            pf0[slot] = *(const float4*)(cp + (size_t)(d + 4) * KCODES);
            pf1[slot] = *(const float4*)(cp + (size_t)(d + 4) * KCODES + 4);
            float4 z0 = *(const float4*)(&zt[d * PZ + 8 * ty]);
            float4 z1 = *(const float4*)(&zt[d * PZ + 8 * ty + 4]);
            float zr[8] = {z0.x, z0.y, z0.z, z0.w, z1.x, z1.y, z1.z, z1.w};
            float cr[8] = {c0.x, c0.y, c0.z, c0.w, c1.x, c1.y, c1.z, c1.w};
            #pragma unroll
            for (int i = 0; i < 8; ++i)
                #pragma unroll
                for (int j = 0; j < 8; ++j)
                    acc[i][j] = fmaf(zr[i], cr[j], acc[i][j]);
        }
        #pragma unroll
        for (int d = DDIM - 4; d < DDIM; ++d) {     // drain the ring
            const int slot = d & 3;
            float4 c0 = pf0[slot], c1 = pf1[slot];
            float4 z0 = *(const float4*)(&zt[d * PZ + 8 * ty]);
            float4 z1 = *(const float4*)(&zt[d * PZ + 8 * ty + 4]);
            float zr[8] = {z0.x, z0.y, z0.z, z0.w, z1.x, z1.y, z1.z, z1.w};
            float cr[8] = {c0.x, c0.y, c0.z, c0.w, c1.x, c1.y, c1.z, c1.w};
            #pragma unroll
            for (int i = 0; i < 8; ++i)
                #pragma unroll
                for (int j = 0; j < 8; ++j)
                    acc[i][j] = fmaf(zr[i], cr[j], acc[i][j]);
        }

        float4 cn0 = *(const float4*)(cnorm + kbp + 8 * tx);
        float4 cn1 = *(const float4*)(cnorm + kbp + 8 * tx + 4);
        float cnr[8] = {cn0.x, cn0.y, cn0.z, cn0.w, cn1.x, cn1.y, cn1.z, cn1.w};
        #pragma unroll
        for (int j = 0; j < 8; ++j) {
            int code = kbp + 8 * tx + j;
            #pragma unroll
            for (int i = 0; i < 8; ++i) {
                float s = nofuse(zn_s[8 * ty + i] + cnr[j]);
                float dist = fmaf(-2.0f, acc[i][j], s);   // 2*acc exact (pow2)
                // (p,j) ascend -> per-thread codes ascend; strict < keeps lowest
                if (dist < minv[i]) { minv[i] = dist; mini[i] = code; }
            }
        }
    }

    // ---- argmin across the 32 tx-threads per token (alias zt) ----
    __syncthreads();
    float* rv   = zt;                    // [64][32]
    int*   ri   = (int*)(zt + 2048);     // [64][32]
    int*   wink = (int*)(zt + 4096);     // [64]
    #pragma unroll
    for (int i = 0; i < 8; ++i) {
        rv[(8 * ty + i) * 32 + tx] = minv[i];
        ri[(8 * ty + i) * 32 + tx] = mini[i];
    }
    __syncthreads();
    if (tid < 64) {
        float bv = rv[tid * 32];
        int   bi = ri[tid * 32];
        #pragma unroll
        for (int j = 1; j < 32; ++j) {
            float v  = rv[tid * 32 + j];
            int   ii = ri[tid * 32 + j];
            if (v < bv || (v == bv && ii < bi)) { bv = v; bi = ii; }
        }
        wink[tid] = bi;
        idxf[t0 + tid] = (float)bi;
    }
    __syncthreads();

    // ---- gather winner rows, z_q write, loss partial ----
    // thread covers token = tid>>2, quarter = tid&3 (32 d's = 8 float4)
    const int token = tid >> 2;
    const int part  = tid & 3;
    const int bk    = wink[token];
    float lsum = 0.0f;
    #pragma unroll
    for (int jj = 0; jj < 8; ++jj) {
        int d4 = part * 8 + jj;
        float4 cv = *(const float4*)(cb + (size_t)bk * DDIM + 4 * d4);
        float4 zv = *(const float4*)(z + (size_t)(t0 + token) * DDIM + 4 * d4);
        *(float4*)(zq + (size_t)(t0 + token) * DDIM + 4 * d4) = cv;
        float dx = cv.x - zv.x, dy = cv.y - zv.y;
        float dz2 = cv.z - zv.z, dw = cv.w - zv.w;
        lsum += dx * dx + dy * dy + dz2 * dz2 + dw * dw;
    }
    #pragma unroll
    for (int off = 32; off > 0; off >>= 1) lsum += __shfl_down(lsum, off);
    if (lane == 0) sm[wv] = lsum;
    __syncthreads();
    if (tid == 0) {
        float blk = (sm[0] + sm[1] + sm[2] + sm[3]) * (1.25f / (float)((size_t)NTOK * DDIM));
        atomicAdd(loss_accum, blk);      // loss_accum IS the output slot
    }
}

extern "C" void kernel_launch(void* const* d_in, const int* in_sizes, int n_in,
                              void* d_out, int out_size, void* d_ws, size_t ws_size,
                              hipStream_t stream) {
    const float* z  = (const float*)d_in[0];   // [32768,128]
    const float* cb = (const float*)d_in[1];   // [1024,128]
    float* out  = (float*)d_out;
    float* zq   = out;                         // 4194304
    float* loss = out + (size_t)NTOK * DDIM;   // 1  (accumulated in place)
    float* idxf = loss + 1;                    // 32768

    float* cbT   = (float*)d_ws;                  // 128*1024 = 512KB
    float* cnorm = cbT + (size_t)DDIM * KCODES;   // 1024

    prep_cb<<<KCODES / 32, 256, 0, stream>>>(cb, cbT, cnorm, loss);
    vq_fused<<<NTOK / 64, 256, 0, stream>>>(z, cb, cbT, cnorm, zq, idxf, loss);
}